// Round 1
// baseline (300.961 us; speedup 1.0000x reference)
//
#include <hip/hip_runtime.h>

typedef unsigned short u16;
typedef unsigned int u32;
typedef __bf16 bf16x8 __attribute__((ext_vector_type(8)));
typedef float f32x4 __attribute__((ext_vector_type(4)));

#define S_LEN 2048
#define D_MODEL 2048
#define DK_ 512

__device__ __forceinline__ u16 f2b(float f) {
  u32 u = __float_as_uint(f);
  return (u16)((u + 0x7fffu + ((u >> 16) & 1u)) >> 16);
}

// ---------------- fused fp32 -> bf16 cast of x, Wq, Wk, Wv, Wo ----------------
__global__ __launch_bounds__(256) void cast_all_kernel(
    const float* __restrict__ x, const float* __restrict__ wq,
    const float* __restrict__ wk, const float* __restrict__ wv,
    const float* __restrict__ wo,
    u16* __restrict__ xb, u16* __restrict__ wqb, u16* __restrict__ wkb,
    u16* __restrict__ wvb, u16* __restrict__ wob)
{
  long i4 = (long)blockIdx.x * 256 + threadIdx.x;  // vec4 index
  const float* src; u16* dst; long off;
  if (i4 < 1048576)       { src = x;  dst = xb;  off = i4; }
  else if (i4 < 2097152)  { src = wq; dst = wqb; off = i4 - 1048576; }
  else if (i4 < 2359296)  { src = wk; dst = wkb; off = i4 - 2097152; }
  else if (i4 < 2621440)  { src = wv; dst = wvb; off = i4 - 2359296; }
  else                    { src = wo; dst = wob; off = i4 - 2621440; }
  float4 v = *(const float4*)(src + off * 4);
  ushort4 o;
  o.x = f2b(v.x); o.y = f2b(v.y); o.z = f2b(v.z); o.w = f2b(v.w);
  *(ushort4*)(dst + off * 4) = o;
}

// ---------------- GEMM: C = A @ B^T.  A[M,K], B[N,K] bf16 row-major ----------
// EPI 0: bf16 store. EPI 1: fused RoPE-quirk epilogue (shifted col + sign + pm
// scale), bf16 store. EPI 2: fp32 store.
template<int EPI>
__global__ __launch_bounds__(256) void gemm_bt(
    const u16* __restrict__ A, const u16* __restrict__ B, void* __restrict__ Cv,
    int M, int N, int K, const float* __restrict__ pm, int d)
{
  __shared__ u16 As[128 * 64];
  __shared__ u16 Bs[128 * 64];
  const int tid = threadIdx.x;
  const int lane = tid & 63, w = tid >> 6;
  const int wr = w >> 1, wc = w & 1;
  const int l15 = lane & 15, l4 = lane >> 4;
  const int m0 = blockIdx.y * 128, n0 = blockIdx.x * 128;

  const f32x4 z4 = {0.f, 0.f, 0.f, 0.f};
  f32x4 acc[4][4];
#pragma unroll
  for (int i = 0; i < 4; ++i)
#pragma unroll
    for (int j = 0; j < 4; ++j) acc[i][j] = z4;

  for (int kt = 0; kt < K; kt += 64) {
    __syncthreads();
#pragma unroll
    for (int i = 0; i < 4; ++i) {
      const int c = i * 256 + tid;
      const int r = c >> 3, c8 = (c & 7) << 3;
      *(uint4*)(&As[r * 64 + c8]) = *(const uint4*)(A + (size_t)(m0 + r) * K + kt + c8);
      *(uint4*)(&Bs[r * 64 + c8]) = *(const uint4*)(B + (size_t)(n0 + r) * K + kt + c8);
    }
    __syncthreads();
#pragma unroll
    for (int ks = 0; ks < 2; ++ks) {
      bf16x8 a[4], b[4];
#pragma unroll
      for (int mt = 0; mt < 4; ++mt)
        a[mt] = *(const bf16x8*)(&As[(wr * 64 + mt * 16 + l15) * 64 + ks * 32 + l4 * 8]);
#pragma unroll
      for (int nt = 0; nt < 4; ++nt)
        b[nt] = *(const bf16x8*)(&Bs[(wc * 64 + nt * 16 + l15) * 64 + ks * 32 + l4 * 8]);
#pragma unroll
      for (int mt = 0; mt < 4; ++mt)
#pragma unroll
        for (int nt = 0; nt < 4; ++nt)
          acc[mt][nt] = __builtin_amdgcn_mfma_f32_16x16x32_bf16(a[mt], b[nt], acc[mt][nt], 0, 0, 0);
    }
  }

#pragma unroll
  for (int mt = 0; mt < 4; ++mt)
#pragma unroll
    for (int nt = 0; nt < 4; ++nt)
#pragma unroll
      for (int j = 0; j < 4; ++j) {
        const int m = m0 + wr * 64 + mt * 16 + l4 * 4 + j;
        const int n = n0 + wc * 64 + nt * 16 + l15;
        const float v = acc[mt][nt][j];
        if (EPI == 0) {
          ((u16*)Cv)[(size_t)m * N + n] = f2b(v);
        } else if (EPI == 2) {
          ((float*)Cv)[(size_t)m * N + n] = v;
        } else {
          // raw col n -> output col jj, sign: n < d/2 ? + : -
          const int d2 = d >> 1;
          const int jj = (n < d2) ? (n + d2) : (n - d2);
          const float sv = (n < d2) ? v : -v;
          const float p = pm[(size_t)m * D_MODEL + jj] +
                          pm[(size_t)S_LEN * D_MODEL + (size_t)m * D_MODEL + jj];
          ((u16*)Cv)[(size_t)m * N + jj] = f2b(sv * p);
        }
      }
}

// ---------------- bf16 transpose: in[R][C] -> out[C][R] ----------------------
__global__ __launch_bounds__(256) void transpose_bf16(
    const u16* __restrict__ in, u16* __restrict__ out, int R, int C)
{
  __shared__ u16 t[32][33];
  const int c0 = blockIdx.x * 32, r0 = blockIdx.y * 32;
  const int x = threadIdx.x, y = threadIdx.y;  // blockDim = (32, 8)
#pragma unroll
  for (int j = 0; j < 32; j += 8)
    t[y + j][x] = in[(size_t)(r0 + y + j) * C + c0 + x];
  __syncthreads();
#pragma unroll
  for (int j = 0; j < 32; j += 8)
    out[(size_t)(c0 + y + j) * R + r0 + x] = t[x][y + j];
}

// ---------------- fused attention ------------------------------------------
// Q: qro [S][2048] bf16 (rope'd). Kx: kro [S][512] bf16 (rope'd).
// Vt: xv^T [512][S] bf16. O: attn out [S][2048] bf16 (head-major cols).
// Block: 256 thr = 4 waves; each wave owns 32 q rows; KV tiles of 64.
// Non-causal, no online max (scores bounded), denom = sum(e) + 1.
__global__ __launch_bounds__(256) void attn_kernel(
    const u16* __restrict__ Q, const u16* __restrict__ Kx,
    const u16* __restrict__ Vt, u16* __restrict__ O)
{
  __shared__ u16 Ks[64 * 72];        // K tile [t][hd], stride 72 (pad)
  __shared__ u16 Vs[64 * 72];        // V^T tile [hd][t], stride 72
  __shared__ u16 Es[4 * 32 * 72];    // per-wave P tile [q][t], stride 72

  const int tid = threadIdx.x;
  const int lane = tid & 63, w = tid >> 6;
  const int l15 = lane & 15, l4 = lane >> 4;
  const int h = blockIdx.y;
  const int q0 = blockIdx.x * 128;
  const int hk = (h & 7) * 64;       // kv column base (GQA: kv head = h%8)
  const float scale = 0.04419417187f;  // 1/(sqrt(512)+1e-6)

  // Q fragments: rows = q, k = hd (A-operand layout)
  bf16x8 aq[2][2];
#pragma unroll
  for (int mt = 0; mt < 2; ++mt)
#pragma unroll
    for (int ks = 0; ks < 2; ++ks)
      aq[mt][ks] = *(const bf16x8*)(Q + (size_t)(q0 + w * 32 + mt * 16 + l15) * D_MODEL
                                      + h * 64 + ks * 32 + l4 * 8);

  const f32x4 z4 = {0.f, 0.f, 0.f, 0.f};
  f32x4 o[2][4];
  float denom[2][4];
#pragma unroll
  for (int mt = 0; mt < 2; ++mt)
#pragma unroll
    for (int nt = 0; nt < 4; ++nt) o[mt][nt] = z4;
#pragma unroll
  for (int mt = 0; mt < 2; ++mt)
#pragma unroll
    for (int j = 0; j < 4; ++j) denom[mt][j] = 0.f;

  u16* Ew = Es + w * (32 * 72);

  for (int t0 = 0; t0 < S_LEN; t0 += 64) {
    __syncthreads();
#pragma unroll
    for (int i = 0; i < 2; ++i) {
      const int c = i * 256 + tid;
      const int r = c >> 3, c8 = (c & 7) << 3;
      *(uint4*)(&Ks[r * 72 + c8]) = *(const uint4*)(Kx + (size_t)(t0 + r) * DK_ + hk + c8);
      *(uint4*)(&Vs[r * 72 + c8]) = *(const uint4*)(Vt + (size_t)(hk + r) * S_LEN + t0 + c8);
    }
    __syncthreads();

    // QK^T: s[mt][tt] covers q=[mt*16,+16) x t=[tt*16,+16)
    f32x4 s[2][4];
#pragma unroll
    for (int mt = 0; mt < 2; ++mt)
#pragma unroll
      for (int tt = 0; tt < 4; ++tt) s[mt][tt] = z4;
#pragma unroll
    for (int ks = 0; ks < 2; ++ks) {
      bf16x8 bk[4];
#pragma unroll
      for (int tt = 0; tt < 4; ++tt)
        bk[tt] = *(const bf16x8*)(&Ks[(tt * 16 + l15) * 72 + ks * 32 + l4 * 8]);
#pragma unroll
      for (int mt = 0; mt < 2; ++mt)
#pragma unroll
        for (int tt = 0; tt < 4; ++tt)
          s[mt][tt] = __builtin_amdgcn_mfma_f32_16x16x32_bf16(aq[mt][ks], bk[tt], s[mt][tt], 0, 0, 0);
    }

    // exp + denom partial sums + stage P tile in LDS (D-layout -> A-layout fix)
#pragma unroll
    for (int mt = 0; mt < 2; ++mt) {
      float ds[4] = {0.f, 0.f, 0.f, 0.f};
#pragma unroll
      for (int tt = 0; tt < 4; ++tt)
#pragma unroll
        for (int j = 0; j < 4; ++j) {
          const float e = __expf(s[mt][tt][j] * scale);
          ds[j] += e;
          Ew[(mt * 16 + l4 * 4 + j) * 72 + tt * 16 + l15] = f2b(e);
        }
#pragma unroll
      for (int j = 0; j < 4; ++j) {
        float v = ds[j];
        v += __shfl_xor(v, 1);
        v += __shfl_xor(v, 2);
        v += __shfl_xor(v, 4);
        v += __shfl_xor(v, 8);
        denom[mt][j] += v;
      }
    }

    // PV: o[mt][nt] += P[q, t] @ V[t, hd]
#pragma unroll
    for (int ks = 0; ks < 2; ++ks) {
      bf16x8 bv[4];
#pragma unroll
      for (int nt = 0; nt < 4; ++nt)
        bv[nt] = *(const bf16x8*)(&Vs[(nt * 16 + l15) * 72 + ks * 32 + l4 * 8]);
#pragma unroll
      for (int mt = 0; mt < 2; ++mt) {
        const bf16x8 ae = *(const bf16x8*)(&Ew[(mt * 16 + l15) * 72 + ks * 32 + l4 * 8]);
#pragma unroll
        for (int nt = 0; nt < 4; ++nt)
          o[mt][nt] = __builtin_amdgcn_mfma_f32_16x16x32_bf16(ae, bv[nt], o[mt][nt], 0, 0, 0);
      }
    }
  }

  // normalize + store
#pragma unroll
  for (int mt = 0; mt < 2; ++mt)
#pragma unroll
    for (int nt = 0; nt < 4; ++nt)
#pragma unroll
      for (int j = 0; j < 4; ++j) {
        const float val = o[mt][nt][j] / (denom[mt][j] + 1.0f);
        O[(size_t)(q0 + w * 32 + mt * 16 + l4 * 4 + j) * D_MODEL
          + h * 64 + nt * 16 + l15] = f2b(val);
      }
}

// ---------------------------------------------------------------------------
extern "C" void kernel_launch(void* const* d_in, const int* in_sizes, int n_in,
                              void* d_out, int out_size, void* d_ws, size_t ws_size,
                              hipStream_t stream) {
  const float* x  = (const float*)d_in[0];
  const float* pm = (const float*)d_in[1];
  const float* Wq = (const float*)d_in[2];
  const float* Wk = (const float*)d_in[3];
  const float* Wv = (const float*)d_in[4];
  const float* Wo = (const float*)d_in[5];
  float* outp = (float*)d_out;
  char* ws = (char*)d_ws;

  const size_t MB = 1024 * 1024;
  u16* xb   = (u16*)(ws + 0 * MB);    // x bf16          [2048][2048]  8MB
  u16* wqb  = (u16*)(ws + 8 * MB);    // Wq bf16         [2048][2048]  8MB
  u16* wkb  = (u16*)(ws + 16 * MB);   // Wk bf16         [512][2048]   2MB
  u16* wvb  = (u16*)(ws + 18 * MB);   // Wv bf16         [512][2048]   2MB
  u16* wob  = (u16*)(ws + 20 * MB);   // Wo bf16         [2048][2048]  8MB
  u16* qro  = (u16*)(ws + 28 * MB);   // rope(xq) bf16   [2048][2048]  8MB
  u16* kro  = (u16*)(ws + 36 * MB);   // rope(xk) bf16   [2048][512]   2MB
  u16* xvb  = (u16*)(ws + 38 * MB);   // xv bf16         [2048][512]   2MB
  u16* xvt  = (u16*)(ws + 40 * MB);   // xv^T bf16       [512][2048]   2MB
  u16* attn = (u16*)(ws + 42 * MB);   // attn out bf16   [2048][2048]  8MB

  cast_all_kernel<<<14336, 256, 0, stream>>>(x, Wq, Wk, Wv, Wo, xb, wqb, wkb, wvb, wob);
  // Q projection + fused rope-quirk epilogue
  gemm_bt<1><<<dim3(16, 16), 256, 0, stream>>>(xb, wqb, (void*)qro, 2048, 2048, 2048, pm, 2048);
  // K projection + fused rope-quirk epilogue
  gemm_bt<1><<<dim3(4, 16), 256, 0, stream>>>(xb, wkb, (void*)kro, 2048, 512, 2048, pm, 512);
  // V projection (plain bf16 out)
  gemm_bt<0><<<dim3(4, 16), 256, 0, stream>>>(xb, wvb, (void*)xvb, 2048, 512, 2048, nullptr, 0);
  // V transpose for t-contiguous PV reads
  transpose_bf16<<<dim3(16, 64), dim3(32, 8), 0, stream>>>(xvb, xvt, 2048, 512);
  // fused attention
  attn_kernel<<<dim3(16, 32), 256, 0, stream>>>(qro, kro, xvt, attn);
  // output projection, fp32 out
  gemm_bt<2><<<dim3(16, 16), 256, 0, stream>>>(attn, wob, (void*)outp, 2048, 2048, 2048, nullptr, 0);
}

// Round 2
// 300.913 us; speedup vs baseline: 1.0002x; 1.0002x over previous
//
#include <hip/hip_runtime.h>

typedef unsigned short u16;
typedef unsigned int u32;
typedef __bf16 bf16x8 __attribute__((ext_vector_type(8)));
typedef float f32x4 __attribute__((ext_vector_type(4)));

#define S_LEN 2048
#define D_MODEL 2048
#define DK_ 512

__device__ __forceinline__ u16 f2b(float f) {
  u32 u = __float_as_uint(f);
  return (u16)((u + 0x7fffu + ((u >> 16) & 1u)) >> 16);
}

// ---------------- fused fp32 -> bf16 cast of x, Wq, Wk, Wv, Wo ----------------
__global__ __launch_bounds__(256) void cast_all_kernel(
    const float* __restrict__ x, const float* __restrict__ wq,
    const float* __restrict__ wk, const float* __restrict__ wv,
    const float* __restrict__ wo,
    u16* __restrict__ xb, u16* __restrict__ wqb, u16* __restrict__ wkb,
    u16* __restrict__ wvb, u16* __restrict__ wob)
{
  long i4 = (long)blockIdx.x * 256 + threadIdx.x;  // vec4 index
  const float* src; u16* dst; long off;
  if (i4 < 1048576)       { src = x;  dst = xb;  off = i4; }
  else if (i4 < 2097152)  { src = wq; dst = wqb; off = i4 - 1048576; }
  else if (i4 < 2359296)  { src = wk; dst = wkb; off = i4 - 2097152; }
  else if (i4 < 2621440)  { src = wv; dst = wvb; off = i4 - 2359296; }
  else                    { src = wo; dst = wob; off = i4 - 2621440; }
  float4 v = *(const float4*)(src + off * 4);
  ushort4 o;
  o.x = f2b(v.x); o.y = f2b(v.y); o.z = f2b(v.z); o.w = f2b(v.w);
  *(ushort4*)(dst + off * 4) = o;
}

// ---------------- GEMM: C = A @ B^T.  A[M,K], B[N,K] bf16 row-major ----------
// EPI 0: bf16 store. EPI 1: fused RoPE-quirk epilogue (shifted col + sign + pm
// scale), bf16 store. EPI 2: fp32 store.
template<int EPI>
__global__ __launch_bounds__(256) void gemm_bt(
    const u16* __restrict__ A, const u16* __restrict__ B, void* __restrict__ Cv,
    int M, int N, int K, const float* __restrict__ pm, int d)
{
  __shared__ u16 As[128 * 64];
  __shared__ u16 Bs[128 * 64];
  const int tid = threadIdx.x;
  const int lane = tid & 63, w = tid >> 6;
  const int wr = w >> 1, wc = w & 1;
  const int l15 = lane & 15, l4 = lane >> 4;
  const int m0 = blockIdx.y * 128, n0 = blockIdx.x * 128;

  const f32x4 z4 = {0.f, 0.f, 0.f, 0.f};
  f32x4 acc[4][4];
#pragma unroll
  for (int i = 0; i < 4; ++i)
#pragma unroll
    for (int j = 0; j < 4; ++j) acc[i][j] = z4;

  for (int kt = 0; kt < K; kt += 64) {
    __syncthreads();
#pragma unroll
    for (int i = 0; i < 4; ++i) {
      const int c = i * 256 + tid;
      const int r = c >> 3, c8 = (c & 7) << 3;
      *(uint4*)(&As[r * 64 + c8]) = *(const uint4*)(A + (size_t)(m0 + r) * K + kt + c8);
      *(uint4*)(&Bs[r * 64 + c8]) = *(const uint4*)(B + (size_t)(n0 + r) * K + kt + c8);
    }
    __syncthreads();
#pragma unroll
    for (int ks = 0; ks < 2; ++ks) {
      bf16x8 a[4], b[4];
#pragma unroll
      for (int mt = 0; mt < 4; ++mt)
        a[mt] = *(const bf16x8*)(&As[(wr * 64 + mt * 16 + l15) * 64 + ks * 32 + l4 * 8]);
#pragma unroll
      for (int nt = 0; nt < 4; ++nt)
        b[nt] = *(const bf16x8*)(&Bs[(wc * 64 + nt * 16 + l15) * 64 + ks * 32 + l4 * 8]);
#pragma unroll
      for (int mt = 0; mt < 4; ++mt)
#pragma unroll
        for (int nt = 0; nt < 4; ++nt)
          acc[mt][nt] = __builtin_amdgcn_mfma_f32_16x16x32_bf16(a[mt], b[nt], acc[mt][nt], 0, 0, 0);
    }
  }

#pragma unroll
  for (int mt = 0; mt < 4; ++mt)
#pragma unroll
    for (int nt = 0; nt < 4; ++nt)
#pragma unroll
      for (int j = 0; j < 4; ++j) {
        const int m = m0 + wr * 64 + mt * 16 + l4 * 4 + j;
        const int n = n0 + wc * 64 + nt * 16 + l15;
        const float v = acc[mt][nt][j];
        if (EPI == 0) {
          ((u16*)Cv)[(size_t)m * N + n] = f2b(v);
        } else if (EPI == 2) {
          ((float*)Cv)[(size_t)m * N + n] = v;
        } else {
          // raw col n -> output col jj, sign: n < d/2 ? + : -
          const int d2 = d >> 1;
          const int jj = (n < d2) ? (n + d2) : (n - d2);
          const float sv = (n < d2) ? v : -v;
          const float p = pm[(size_t)m * D_MODEL + jj] +
                          pm[(size_t)S_LEN * D_MODEL + (size_t)m * D_MODEL + jj];
          ((u16*)Cv)[(size_t)m * N + jj] = f2b(sv * p);
        }
      }
}

// ---------------- bf16 transpose: in[R][C] -> out[C][R] ----------------------
__global__ __launch_bounds__(256) void transpose_bf16(
    const u16* __restrict__ in, u16* __restrict__ out, int R, int C)
{
  __shared__ u16 t[32][33];
  const int c0 = blockIdx.x * 32, r0 = blockIdx.y * 32;
  const int x = threadIdx.x, y = threadIdx.y;  // blockDim = (32, 8)
#pragma unroll
  for (int j = 0; j < 32; j += 8)
    t[y + j][x] = in[(size_t)(r0 + y + j) * C + c0 + x];
  __syncthreads();
#pragma unroll
  for (int j = 0; j < 32; j += 8)
    out[(size_t)(c0 + y + j) * R + r0 + x] = t[x][y + j];
}

// ---------------- fused attention ------------------------------------------
// Q: qro [S][2048] bf16 (rope'd). Kx: kro [S][512] bf16 (rope'd).
// Vt: xv^T [512][S] bf16. O: attn out [S][2048] bf16 (head-major cols).
// Block: 256 thr = 4 waves; each wave owns 32 q rows; KV tiles of 64.
// Non-causal, no online max (scores bounded), denom = sum(e) + 1.
__global__ __launch_bounds__(256) void attn_kernel(
    const u16* __restrict__ Q, const u16* __restrict__ Kx,
    const u16* __restrict__ Vt, u16* __restrict__ O)
{
  __shared__ u16 Ks[64 * 72];        // K tile [t][hd], stride 72 (pad)
  __shared__ u16 Vs[64 * 72];        // V^T tile [hd][t], stride 72
  __shared__ u16 Es[4 * 32 * 72];    // per-wave P tile [q][t], stride 72

  const int tid = threadIdx.x;
  const int lane = tid & 63, w = tid >> 6;
  const int l15 = lane & 15, l4 = lane >> 4;
  const int h = blockIdx.y;
  const int q0 = blockIdx.x * 128;
  const int hk = (h & 7) * 64;       // kv column base (GQA: kv head = h%8)
  const float scale = 0.04419417187f;  // 1/(sqrt(512)+1e-6)

  // Q fragments: rows = q, k = hd (A-operand layout)
  bf16x8 aq[2][2];
#pragma unroll
  for (int mt = 0; mt < 2; ++mt)
#pragma unroll
    for (int ks = 0; ks < 2; ++ks)
      aq[mt][ks] = *(const bf16x8*)(Q + (size_t)(q0 + w * 32 + mt * 16 + l15) * D_MODEL
                                      + h * 64 + ks * 32 + l4 * 8);

  const f32x4 z4 = {0.f, 0.f, 0.f, 0.f};
  f32x4 o[2][4];
  float denom[2][4];
#pragma unroll
  for (int mt = 0; mt < 2; ++mt)
#pragma unroll
    for (int nt = 0; nt < 4; ++nt) o[mt][nt] = z4;
#pragma unroll
  for (int mt = 0; mt < 2; ++mt)
#pragma unroll
    for (int j = 0; j < 4; ++j) denom[mt][j] = 0.f;

  u16* Ew = Es + w * (32 * 72);

  for (int t0 = 0; t0 < S_LEN; t0 += 64) {
    __syncthreads();
#pragma unroll
    for (int i = 0; i < 2; ++i) {
      const int c = i * 256 + tid;
      const int r = c >> 3, c8 = (c & 7) << 3;
      *(uint4*)(&Ks[r * 72 + c8]) = *(const uint4*)(Kx + (size_t)(t0 + r) * DK_ + hk + c8);
      *(uint4*)(&Vs[r * 72 + c8]) = *(const uint4*)(Vt + (size_t)(hk + r) * S_LEN + t0 + c8);
    }
    __syncthreads();

    // QK^T: s[mt][tt] covers q=[mt*16,+16) x t=[tt*16,+16)
    f32x4 s[2][4];
#pragma unroll
    for (int mt = 0; mt < 2; ++mt)
#pragma unroll
      for (int tt = 0; tt < 4; ++tt) s[mt][tt] = z4;
#pragma unroll
    for (int ks = 0; ks < 2; ++ks) {
      bf16x8 bk[4];
#pragma unroll
      for (int tt = 0; tt < 4; ++tt)
        bk[tt] = *(const bf16x8*)(&Ks[(tt * 16 + l15) * 72 + ks * 32 + l4 * 8]);
#pragma unroll
      for (int mt = 0; mt < 2; ++mt)
#pragma unroll
        for (int tt = 0; tt < 4; ++tt)
          s[mt][tt] = __builtin_amdgcn_mfma_f32_16x16x32_bf16(aq[mt][ks], bk[tt], s[mt][tt], 0, 0, 0);
    }

    // exp + denom partial sums + stage P tile in LDS (D-layout -> A-layout fix)
#pragma unroll
    for (int mt = 0; mt < 2; ++mt) {
      float ds[4] = {0.f, 0.f, 0.f, 0.f};
#pragma unroll
      for (int tt = 0; tt < 4; ++tt)
#pragma unroll
        for (int j = 0; j < 4; ++j) {
          const float e = __expf(s[mt][tt][j] * scale);
          ds[j] += e;
          Ew[(mt * 16 + l4 * 4 + j) * 72 + tt * 16 + l15] = f2b(e);
        }
#pragma unroll
      for (int j = 0; j < 4; ++j) {
        float v = ds[j];
        v += __shfl_xor(v, 1);
        v += __shfl_xor(v, 2);
        v += __shfl_xor(v, 4);
        v += __shfl_xor(v, 8);
        denom[mt][j] += v;
      }
    }

    // PV: o[mt][nt] += P[q, t] @ V[t, hd]
#pragma unroll
    for (int ks = 0; ks < 2; ++ks) {
      bf16x8 bv[4];
#pragma unroll
      for (int nt = 0; nt < 4; ++nt)
        bv[nt] = *(const bf16x8*)(&Vs[(nt * 16 + l15) * 72 + ks * 32 + l4 * 8]);
#pragma unroll
      for (int mt = 0; mt < 2; ++mt) {
        const bf16x8 ae = *(const bf16x8*)(&Ew[(mt * 16 + l15) * 72 + ks * 32 + l4 * 8]);
#pragma unroll
        for (int nt = 0; nt < 4; ++nt)
          o[mt][nt] = __builtin_amdgcn_mfma_f32_16x16x32_bf16(ae, bv[nt], o[mt][nt], 0, 0, 0);
      }
    }
  }

  // normalize + store
#pragma unroll
  for (int mt = 0; mt < 2; ++mt)
#pragma unroll
    for (int nt = 0; nt < 4; ++nt)
#pragma unroll
      for (int j = 0; j < 4; ++j) {
        const float val = o[mt][nt][j] / (denom[mt][j] + 1.0f);
        O[(size_t)(q0 + w * 32 + mt * 16 + l4 * 4 + j) * D_MODEL
          + h * 64 + nt * 16 + l15] = f2b(val);
      }
}

// ---------------------------------------------------------------------------
extern "C" void kernel_launch(void* const* d_in, const int* in_sizes, int n_in,
                              void* d_out, int out_size, void* d_ws, size_t ws_size,
                              hipStream_t stream) {
  const float* x  = (const float*)d_in[0];
  const float* pm = (const float*)d_in[1];
  const float* Wq = (const float*)d_in[2];
  const float* Wk = (const float*)d_in[3];
  const float* Wv = (const float*)d_in[4];
  const float* Wo = (const float*)d_in[5];
  float* outp = (float*)d_out;
  char* ws = (char*)d_ws;

  const size_t MB = 1024 * 1024;
  u16* xb   = (u16*)(ws + 0 * MB);    // x bf16          [2048][2048]  8MB
  u16* wqb  = (u16*)(ws + 8 * MB);    // Wq bf16         [2048][2048]  8MB
  u16* wkb  = (u16*)(ws + 16 * MB);   // Wk bf16         [512][2048]   2MB
  u16* wvb  = (u16*)(ws + 18 * MB);   // Wv bf16         [512][2048]   2MB
  u16* wob  = (u16*)(ws + 20 * MB);   // Wo bf16         [2048][2048]  8MB
  u16* qro  = (u16*)(ws + 28 * MB);   // rope(xq) bf16   [2048][2048]  8MB
  u16* kro  = (u16*)(ws + 36 * MB);   // rope(xk) bf16   [2048][512]   2MB
  u16* xvb  = (u16*)(ws + 38 * MB);   // xv bf16         [2048][512]   2MB
  u16* xvt  = (u16*)(ws + 40 * MB);   // xv^T bf16       [512][2048]   2MB
  u16* attn = (u16*)(ws + 42 * MB);   // attn out bf16   [2048][2048]  8MB

  cast_all_kernel<<<14336, 256, 0, stream>>>(x, Wq, Wk, Wv, Wo, xb, wqb, wkb, wvb, wob);
  // Q projection + fused rope-quirk epilogue
  gemm_bt<1><<<dim3(16, 16), 256, 0, stream>>>(xb, wqb, (void*)qro, 2048, 2048, 2048, pm, 2048);
  // K projection + fused rope-quirk epilogue
  gemm_bt<1><<<dim3(4, 16), 256, 0, stream>>>(xb, wkb, (void*)kro, 2048, 512, 2048, pm, 512);
  // V projection (plain bf16 out)
  gemm_bt<0><<<dim3(4, 16), 256, 0, stream>>>(xb, wvb, (void*)xvb, 2048, 512, 2048, nullptr, 0);
  // V transpose for t-contiguous PV reads
  transpose_bf16<<<dim3(16, 64), dim3(32, 8), 0, stream>>>(xvb, xvt, 2048, 512);
  // fused attention
  attn_kernel<<<dim3(16, 32), 256, 0, stream>>>(qro, kro, xvt, attn);
  // output projection, fp32 out
  gemm_bt<2><<<dim3(16, 16), 256, 0, stream>>>(attn, wob, (void*)outp, 2048, 2048, 2048, nullptr, 0);
}

// Round 3
// 300.777 us; speedup vs baseline: 1.0006x; 1.0005x over previous
//
#include <hip/hip_runtime.h>

typedef unsigned short u16;
typedef unsigned int u32;
typedef __bf16 bf16x8 __attribute__((ext_vector_type(8)));
typedef float f32x4 __attribute__((ext_vector_type(4)));

#define S_LEN 2048
#define D_MODEL 2048
#define DK_ 512

__device__ __forceinline__ u16 f2b(float f) {
  u32 u = __float_as_uint(f);
  return (u16)((u + 0x7fffu + ((u >> 16) & 1u)) >> 16);
}

// ---------------- fused fp32 -> bf16 cast of x, Wq, Wk, Wv, Wo ----------------
__global__ __launch_bounds__(256) void cast_all_kernel(
    const float* __restrict__ x, const float* __restrict__ wq,
    const float* __restrict__ wk, const float* __restrict__ wv,
    const float* __restrict__ wo,
    u16* __restrict__ xb, u16* __restrict__ wqb, u16* __restrict__ wkb,
    u16* __restrict__ wvb, u16* __restrict__ wob)
{
  long i4 = (long)blockIdx.x * 256 + threadIdx.x;  // vec4 index
  const float* src; u16* dst; long off;
  if (i4 < 1048576)       { src = x;  dst = xb;  off = i4; }
  else if (i4 < 2097152)  { src = wq; dst = wqb; off = i4 - 1048576; }
  else if (i4 < 2359296)  { src = wk; dst = wkb; off = i4 - 2097152; }
  else if (i4 < 2621440)  { src = wv; dst = wvb; off = i4 - 2359296; }
  else                    { src = wo; dst = wob; off = i4 - 2621440; }
  float4 v = *(const float4*)(src + off * 4);
  ushort4 o;
  o.x = f2b(v.x); o.y = f2b(v.y); o.z = f2b(v.z); o.w = f2b(v.w);
  *(ushort4*)(dst + off * 4) = o;
}

// ---------------- GEMM: C = A @ B^T.  A[M,K], B[N,K] bf16 row-major ----------
// EPI 0: bf16 store. EPI 1: fused RoPE-quirk epilogue (shifted col + sign + pm
// scale), bf16 store. EPI 2: fp32 store.
template<int EPI>
__global__ __launch_bounds__(256) void gemm_bt(
    const u16* __restrict__ A, const u16* __restrict__ B, void* __restrict__ Cv,
    int M, int N, int K, const float* __restrict__ pm, int d)
{
  __shared__ u16 As[128 * 64];
  __shared__ u16 Bs[128 * 64];
  const int tid = threadIdx.x;
  const int lane = tid & 63, w = tid >> 6;
  const int wr = w >> 1, wc = w & 1;
  const int l15 = lane & 15, l4 = lane >> 4;
  const int m0 = blockIdx.y * 128, n0 = blockIdx.x * 128;

  const f32x4 z4 = {0.f, 0.f, 0.f, 0.f};
  f32x4 acc[4][4];
#pragma unroll
  for (int i = 0; i < 4; ++i)
#pragma unroll
    for (int j = 0; j < 4; ++j) acc[i][j] = z4;

  for (int kt = 0; kt < K; kt += 64) {
    __syncthreads();
#pragma unroll
    for (int i = 0; i < 4; ++i) {
      const int c = i * 256 + tid;
      const int r = c >> 3, c8 = (c & 7) << 3;
      *(uint4*)(&As[r * 64 + c8]) = *(const uint4*)(A + (size_t)(m0 + r) * K + kt + c8);
      *(uint4*)(&Bs[r * 64 + c8]) = *(const uint4*)(B + (size_t)(n0 + r) * K + kt + c8);
    }
    __syncthreads();
#pragma unroll
    for (int ks = 0; ks < 2; ++ks) {
      bf16x8 a[4], b[4];
#pragma unroll
      for (int mt = 0; mt < 4; ++mt)
        a[mt] = *(const bf16x8*)(&As[(wr * 64 + mt * 16 + l15) * 64 + ks * 32 + l4 * 8]);
#pragma unroll
      for (int nt = 0; nt < 4; ++nt)
        b[nt] = *(const bf16x8*)(&Bs[(wc * 64 + nt * 16 + l15) * 64 + ks * 32 + l4 * 8]);
#pragma unroll
      for (int mt = 0; mt < 4; ++mt)
#pragma unroll
        for (int nt = 0; nt < 4; ++nt)
          acc[mt][nt] = __builtin_amdgcn_mfma_f32_16x16x32_bf16(a[mt], b[nt], acc[mt][nt], 0, 0, 0);
    }
  }

#pragma unroll
  for (int mt = 0; mt < 4; ++mt)
#pragma unroll
    for (int nt = 0; nt < 4; ++nt)
#pragma unroll
      for (int j = 0; j < 4; ++j) {
        const int m = m0 + wr * 64 + mt * 16 + l4 * 4 + j;
        const int n = n0 + wc * 64 + nt * 16 + l15;
        const float v = acc[mt][nt][j];
        if (EPI == 0) {
          ((u16*)Cv)[(size_t)m * N + n] = f2b(v);
        } else if (EPI == 2) {
          ((float*)Cv)[(size_t)m * N + n] = v;
        } else {
          // raw col n -> output col jj, sign: n < d/2 ? + : -
          const int d2 = d >> 1;
          const int jj = (n < d2) ? (n + d2) : (n - d2);
          const float sv = (n < d2) ? v : -v;
          const float p = pm[(size_t)m * D_MODEL + jj] +
                          pm[(size_t)S_LEN * D_MODEL + (size_t)m * D_MODEL + jj];
          ((u16*)Cv)[(size_t)m * N + jj] = f2b(sv * p);
        }
      }
}

// ---------------- bf16 transpose: in[R][C] -> out[C][R] ----------------------
__global__ __launch_bounds__(256) void transpose_bf16(
    const u16* __restrict__ in, u16* __restrict__ out, int R, int C)
{
  __shared__ u16 t[32][33];
  const int c0 = blockIdx.x * 32, r0 = blockIdx.y * 32;
  const int x = threadIdx.x, y = threadIdx.y;  // blockDim = (32, 8)
#pragma unroll
  for (int j = 0; j < 32; j += 8)
    t[y + j][x] = in[(size_t)(r0 + y + j) * C + c0 + x];
  __syncthreads();
#pragma unroll
  for (int j = 0; j < 32; j += 8)
    out[(size_t)(c0 + y + j) * R + r0 + x] = t[x][y + j];
}

// ---------------- fused attention ------------------------------------------
// Q: qro [S][2048] bf16 (rope'd). Kx: kro [S][512] bf16 (rope'd).
// Vt: xv^T [512][S] bf16. O: attn out [S][2048] bf16 (head-major cols).
// Block: 256 thr = 4 waves; each wave owns 32 q rows; KV tiles of 64.
// Non-causal, no online max (scores bounded), denom = sum(e) + 1.
__global__ __launch_bounds__(256) void attn_kernel(
    const u16* __restrict__ Q, const u16* __restrict__ Kx,
    const u16* __restrict__ Vt, u16* __restrict__ O)
{
  __shared__ u16 Ks[64 * 72];        // K tile [t][hd], stride 72 (pad)
  __shared__ u16 Vs[64 * 72];        // V^T tile [hd][t], stride 72
  __shared__ u16 Es[4 * 32 * 72];    // per-wave P tile [q][t], stride 72

  const int tid = threadIdx.x;
  const int lane = tid & 63, w = tid >> 6;
  const int l15 = lane & 15, l4 = lane >> 4;
  const int h = blockIdx.y;
  const int q0 = blockIdx.x * 128;
  const int hk = (h & 7) * 64;       // kv column base (GQA: kv head = h%8)
  const float scale = 0.04419417187f;  // 1/(sqrt(512)+1e-6)

  // Q fragments: rows = q, k = hd (A-operand layout)
  bf16x8 aq[2][2];
#pragma unroll
  for (int mt = 0; mt < 2; ++mt)
#pragma unroll
    for (int ks = 0; ks < 2; ++ks)
      aq[mt][ks] = *(const bf16x8*)(Q + (size_t)(q0 + w * 32 + mt * 16 + l15) * D_MODEL
                                      + h * 64 + ks * 32 + l4 * 8);

  const f32x4 z4 = {0.f, 0.f, 0.f, 0.f};
  f32x4 o[2][4];
  float denom[2][4];
#pragma unroll
  for (int mt = 0; mt < 2; ++mt)
#pragma unroll
    for (int nt = 0; nt < 4; ++nt) o[mt][nt] = z4;
#pragma unroll
  for (int mt = 0; mt < 2; ++mt)
#pragma unroll
    for (int j = 0; j < 4; ++j) denom[mt][j] = 0.f;

  u16* Ew = Es + w * (32 * 72);

  for (int t0 = 0; t0 < S_LEN; t0 += 64) {
    __syncthreads();
#pragma unroll
    for (int i = 0; i < 2; ++i) {
      const int c = i * 256 + tid;
      const int r = c >> 3, c8 = (c & 7) << 3;
      *(uint4*)(&Ks[r * 72 + c8]) = *(const uint4*)(Kx + (size_t)(t0 + r) * DK_ + hk + c8);
      *(uint4*)(&Vs[r * 72 + c8]) = *(const uint4*)(Vt + (size_t)(hk + r) * S_LEN + t0 + c8);
    }
    __syncthreads();

    // QK^T: s[mt][tt] covers q=[mt*16,+16) x t=[tt*16,+16)
    f32x4 s[2][4];
#pragma unroll
    for (int mt = 0; mt < 2; ++mt)
#pragma unroll
      for (int tt = 0; tt < 4; ++tt) s[mt][tt] = z4;
#pragma unroll
    for (int ks = 0; ks < 2; ++ks) {
      bf16x8 bk[4];
#pragma unroll
      for (int tt = 0; tt < 4; ++tt)
        bk[tt] = *(const bf16x8*)(&Ks[(tt * 16 + l15) * 72 + ks * 32 + l4 * 8]);
#pragma unroll
      for (int mt = 0; mt < 2; ++mt)
#pragma unroll
        for (int tt = 0; tt < 4; ++tt)
          s[mt][tt] = __builtin_amdgcn_mfma_f32_16x16x32_bf16(aq[mt][ks], bk[tt], s[mt][tt], 0, 0, 0);
    }

    // exp + denom partial sums + stage P tile in LDS (D-layout -> A-layout fix)
#pragma unroll
    for (int mt = 0; mt < 2; ++mt) {
      float ds[4] = {0.f, 0.f, 0.f, 0.f};
#pragma unroll
      for (int tt = 0; tt < 4; ++tt)
#pragma unroll
        for (int j = 0; j < 4; ++j) {
          const float e = __expf(s[mt][tt][j] * scale);
          ds[j] += e;
          Ew[(mt * 16 + l4 * 4 + j) * 72 + tt * 16 + l15] = f2b(e);
        }
#pragma unroll
      for (int j = 0; j < 4; ++j) {
        float v = ds[j];
        v += __shfl_xor(v, 1);
        v += __shfl_xor(v, 2);
        v += __shfl_xor(v, 4);
        v += __shfl_xor(v, 8);
        denom[mt][j] += v;
      }
    }

    // PV: o[mt][nt] += P[q, t] @ V[t, hd]
#pragma unroll
    for (int ks = 0; ks < 2; ++ks) {
      bf16x8 bv[4];
#pragma unroll
      for (int nt = 0; nt < 4; ++nt)
        bv[nt] = *(const bf16x8*)(&Vs[(nt * 16 + l15) * 72 + ks * 32 + l4 * 8]);
#pragma unroll
      for (int mt = 0; mt < 2; ++mt) {
        const bf16x8 ae = *(const bf16x8*)(&Ew[(mt * 16 + l15) * 72 + ks * 32 + l4 * 8]);
#pragma unroll
        for (int nt = 0; nt < 4; ++nt)
          o[mt][nt] = __builtin_amdgcn_mfma_f32_16x16x32_bf16(ae, bv[nt], o[mt][nt], 0, 0, 0);
      }
    }
  }

  // normalize + store
#pragma unroll
  for (int mt = 0; mt < 2; ++mt)
#pragma unroll
    for (int nt = 0; nt < 4; ++nt)
#pragma unroll
      for (int j = 0; j < 4; ++j) {
        const float val = o[mt][nt][j] / (denom[mt][j] + 1.0f);
        O[(size_t)(q0 + w * 32 + mt * 16 + l4 * 4 + j) * D_MODEL
          + h * 64 + nt * 16 + l15] = f2b(val);
      }
}

// ---------------------------------------------------------------------------
extern "C" void kernel_launch(void* const* d_in, const int* in_sizes, int n_in,
                              void* d_out, int out_size, void* d_ws, size_t ws_size,
                              hipStream_t stream) {
  const float* x  = (const float*)d_in[0];
  const float* pm = (const float*)d_in[1];
  const float* Wq = (const float*)d_in[2];
  const float* Wk = (const float*)d_in[3];
  const float* Wv = (const float*)d_in[4];
  const float* Wo = (const float*)d_in[5];
  float* outp = (float*)d_out;
  char* ws = (char*)d_ws;

  const size_t MB = 1024 * 1024;
  u16* xb   = (u16*)(ws + 0 * MB);    // x bf16          [2048][2048]  8MB
  u16* wqb  = (u16*)(ws + 8 * MB);    // Wq bf16         [2048][2048]  8MB
  u16* wkb  = (u16*)(ws + 16 * MB);   // Wk bf16         [512][2048]   2MB
  u16* wvb  = (u16*)(ws + 18 * MB);   // Wv bf16         [512][2048]   2MB
  u16* wob  = (u16*)(ws + 20 * MB);   // Wo bf16         [2048][2048]  8MB
  u16* qro  = (u16*)(ws + 28 * MB);   // rope(xq) bf16   [2048][2048]  8MB
  u16* kro  = (u16*)(ws + 36 * MB);   // rope(xk) bf16   [2048][512]   2MB
  u16* xvb  = (u16*)(ws + 38 * MB);   // xv bf16         [2048][512]   2MB
  u16* xvt  = (u16*)(ws + 40 * MB);   // xv^T bf16       [512][2048]   2MB
  u16* attn = (u16*)(ws + 42 * MB);   // attn out bf16   [2048][2048]  8MB

  cast_all_kernel<<<14336, 256, 0, stream>>>(x, Wq, Wk, Wv, Wo, xb, wqb, wkb, wvb, wob);
  // Q projection + fused rope-quirk epilogue
  gemm_bt<1><<<dim3(16, 16), 256, 0, stream>>>(xb, wqb, (void*)qro, 2048, 2048, 2048, pm, 2048);
  // K projection + fused rope-quirk epilogue
  gemm_bt<1><<<dim3(4, 16), 256, 0, stream>>>(xb, wkb, (void*)kro, 2048, 512, 2048, pm, 512);
  // V projection (plain bf16 out)
  gemm_bt<0><<<dim3(4, 16), 256, 0, stream>>>(xb, wvb, (void*)xvb, 2048, 512, 2048, nullptr, 0);
  // V transpose for t-contiguous PV reads
  transpose_bf16<<<dim3(16, 64), dim3(32, 8), 0, stream>>>(xvb, xvt, 2048, 512);
  // fused attention
  attn_kernel<<<dim3(16, 32), 256, 0, stream>>>(qro, kro, xvt, attn);
  // output projection, fp32 out
  gemm_bt<2><<<dim3(16, 16), 256, 0, stream>>>(attn, wob, (void*)outp, 2048, 2048, 2048, nullptr, 0);
}

// Round 4
// 199.161 us; speedup vs baseline: 1.5111x; 1.5102x over previous
//
#include <hip/hip_runtime.h>

typedef unsigned short u16;
typedef unsigned int u32;
typedef __bf16 bf16x8 __attribute__((ext_vector_type(8)));
typedef float f32x4 __attribute__((ext_vector_type(4)));

#define S_LEN 2048
#define D_MODEL 2048
#define DK_ 512
#define PM1_OFF 4194304   // offset of pm[1] in floats (1*1*2048*2048)

__device__ __forceinline__ u16 f2b(float f) {
  u32 u = __float_as_uint(f);
  return (u16)((u + 0x7fffu + ((u >> 16) & 1u)) >> 16);
}

__device__ __forceinline__ void gload_lds16(const void* gp, void* lp) {
  __builtin_amdgcn_global_load_lds(
      (const __attribute__((address_space(1))) void*)gp,
      (__attribute__((address_space(3))) void*)lp, 16, 0, 0);
}

// ---------------- fused fp32 -> bf16 cast of x, Wq, Wk, Wv, Wo ----------------
__global__ __launch_bounds__(256) void cast_all_kernel(
    const float* __restrict__ x, const float* __restrict__ wq,
    const float* __restrict__ wk, const float* __restrict__ wv,
    const float* __restrict__ wo,
    u16* __restrict__ xb, u16* __restrict__ wqb, u16* __restrict__ wkb,
    u16* __restrict__ wvb, u16* __restrict__ wob)
{
  long i4 = (long)blockIdx.x * 256 + threadIdx.x;  // vec4 index
  const float* src; u16* dst; long off;
  if (i4 < 1048576)       { src = x;  dst = xb;  off = i4; }
  else if (i4 < 2097152)  { src = wq; dst = wqb; off = i4 - 1048576; }
  else if (i4 < 2359296)  { src = wk; dst = wkb; off = i4 - 2097152; }
  else if (i4 < 2621440)  { src = wv; dst = wvb; off = i4 - 2359296; }
  else                    { src = wo; dst = wob; off = i4 - 2621440; }
  float4 v = *(const float4*)(src + off * 4);
  ushort4 o;
  o.x = f2b(v.x); o.y = f2b(v.y); o.z = f2b(v.z); o.w = f2b(v.w);
  *(ushort4*)(dst + off * 4) = o;
}

// ---------------- GEMM: C = A @ B^T.  A[M,K], B[N,K] bf16 row-major ----------
// m97-style staging: global_load_lds dwordx4, linear LDS [128][64].
// EPI 1: fused QKV epilogue (n<2048: rope-Q -> C0; n<2560: rope-K -> C1;
//        else plain V -> C2), bf16 stores.
// EPI 2: plain fp32 store to C0.
template<int EPI>
__global__ __launch_bounds__(256) void gemm_bt(
    const u16* __restrict__ A, const u16* __restrict__ B,
    void* __restrict__ C0, void* __restrict__ C1, void* __restrict__ C2,
    int M, int N, int K, const float* __restrict__ pm)
{
  __shared__ u16 As[128 * 64];
  __shared__ u16 Bs[128 * 64];
  const int tid = threadIdx.x;
  const int lane = tid & 63, w = tid >> 6;
  const int wr = w >> 1, wc = w & 1;
  const int l15 = lane & 15, l4 = lane >> 4;
  const int m0 = blockIdx.y * 128, n0 = blockIdx.x * 128;

  // staging: thread tid stages 16B per issue; issue i covers LDS bytes
  // [i*4096 + tid*16) -> row i*32 + tid/8, col-u16 (tid&7)*8.
  const int srow = tid >> 3;           // 0..31
  const int scol = (tid & 7) << 3;     // u16 col
  char* lA = (char*)As + ((tid >> 6) << 10);   // wave-uniform base
  char* lB = (char*)Bs + ((tid >> 6) << 10);
  const u16* gA = A + (size_t)(m0 + srow) * K + scol;
  const u16* gB = B + (size_t)(n0 + srow) * K + scol;

  const f32x4 z4 = {0.f, 0.f, 0.f, 0.f};
  f32x4 acc[4][4];
#pragma unroll
  for (int i = 0; i < 4; ++i)
#pragma unroll
    for (int j = 0; j < 4; ++j) acc[i][j] = z4;

  for (int kt = 0; kt < K; kt += 64) {
    __syncthreads();
#pragma unroll
    for (int i = 0; i < 4; ++i) {
      gload_lds16(gA + (size_t)(i * 32) * K + kt, lA + i * 4096);
      gload_lds16(gB + (size_t)(i * 32) * K + kt, lB + i * 4096);
    }
    __syncthreads();
#pragma unroll
    for (int ks = 0; ks < 2; ++ks) {
      bf16x8 a[4], b[4];
#pragma unroll
      for (int mt = 0; mt < 4; ++mt)
        a[mt] = *(const bf16x8*)(&As[(wr * 64 + mt * 16 + l15) * 64 + ks * 32 + l4 * 8]);
#pragma unroll
      for (int nt = 0; nt < 4; ++nt)
        b[nt] = *(const bf16x8*)(&Bs[(wc * 64 + nt * 16 + l15) * 64 + ks * 32 + l4 * 8]);
#pragma unroll
      for (int mt = 0; mt < 4; ++mt)
#pragma unroll
        for (int nt = 0; nt < 4; ++nt)
          acc[mt][nt] = __builtin_amdgcn_mfma_f32_16x16x32_bf16(a[mt], b[nt], acc[mt][nt], 0, 0, 0);
    }
  }

#pragma unroll
  for (int mt = 0; mt < 4; ++mt)
#pragma unroll
    for (int nt = 0; nt < 4; ++nt)
#pragma unroll
      for (int j = 0; j < 4; ++j) {
        const int m = m0 + wr * 64 + mt * 16 + l4 * 4 + j;
        const int n = n0 + wc * 64 + nt * 16 + l15;
        const float v = acc[mt][nt][j];
        if (EPI == 2) {
          ((float*)C0)[(size_t)m * N + n] = v;
        } else {
          if (n < 2048) {          // Q range, rope d=2048
            const int jj = (n < 1024) ? (n + 1024) : (n - 1024);
            const float sv = (n < 1024) ? v : -v;
            const float p = pm[(size_t)m * D_MODEL + jj] +
                            pm[PM1_OFF + (size_t)m * D_MODEL + jj];
            ((u16*)C0)[(size_t)m * D_MODEL + jj] = f2b(sv * p);
          } else if (n < 2560) {   // K range, rope d=512
            const int nn = n - 2048;
            const int jj = (nn < 256) ? (nn + 256) : (nn - 256);
            const float sv = (nn < 256) ? v : -v;
            const float p = pm[(size_t)m * D_MODEL + jj] +
                            pm[PM1_OFF + (size_t)m * D_MODEL + jj];
            ((u16*)C1)[(size_t)m * DK_ + jj] = f2b(sv * p);
          } else {                 // V range, plain
            ((u16*)C2)[(size_t)m * DK_ + (n - 2560)] = f2b(v);
          }
        }
      }
}

// ---------------- bf16 transpose: in[R][C] -> out[C][R] ----------------------
__global__ __launch_bounds__(256) void transpose_bf16(
    const u16* __restrict__ in, u16* __restrict__ out, int R, int C)
{
  __shared__ u16 t[32][33];
  const int c0 = blockIdx.x * 32, r0 = blockIdx.y * 32;
  const int x = threadIdx.x, y = threadIdx.y;  // blockDim = (32, 8)
#pragma unroll
  for (int j = 0; j < 32; j += 8)
    t[y + j][x] = in[(size_t)(r0 + y + j) * C + c0 + x];
  __syncthreads();
#pragma unroll
  for (int j = 0; j < 32; j += 8)
    out[(size_t)(c0 + y + j) * R + r0 + x] = t[x][y + j];
}

// ---------------- fused attention (swapped QK^T) -----------------------------
// Q: qro [S][2048] bf16. Kx: kro [S][512] bf16. Vt: xv^T [512][S] bf16.
// O: attn out [S][2048] bf16. Block: 256 thr = 4 waves; each wave owns 16 q
// rows; KV tiles of 64. Grid (32, 32) = 1024 blocks -> 16 waves/CU.
// Swapped QK^T: sT = mfma(K, Q) => lane's 4 P-values per frag are
// t-contiguous -> vectorized b64 stores into Es, in-lane denom reduce.
__global__ __launch_bounds__(256) void attn_kernel(
    const u16* __restrict__ Q, const u16* __restrict__ Kx,
    const u16* __restrict__ Vt, u16* __restrict__ O)
{
  __shared__ u16 Ks[64 * 72];        // K tile [t][hd], stride 72 (pad)
  __shared__ u16 Vs[64 * 72];        // V^T tile [hd][t], stride 72
  __shared__ u16 Es[4 * 16 * 72];    // per-wave P tile [q][t], stride 72

  const int tid = threadIdx.x;
  const int lane = tid & 63, w = tid >> 6;
  const int l15 = lane & 15, l4 = lane >> 4;
  const int h = blockIdx.y;
  const int q0 = blockIdx.x * 64 + w * 16;
  const int hk = (h & 7) * 64;       // kv column base (GQA: kv head = h%8)
  const float scale = 0.04419417187f;  // 1/(sqrt(512)+1e-6)

  // Q as B-operand: row q = q0+l15, k-elems hd = ks*32 + l4*8 ..+7
  bf16x8 bq[2];
#pragma unroll
  for (int ks = 0; ks < 2; ++ks)
    bq[ks] = *(const bf16x8*)(Q + (size_t)(q0 + l15) * D_MODEL + h * 64 + ks * 32 + l4 * 8);

  const f32x4 z4 = {0.f, 0.f, 0.f, 0.f};
  f32x4 o[4];
#pragma unroll
  for (int nt = 0; nt < 4; ++nt) o[nt] = z4;
  float denom = 0.f;

  u16* Ew = Es + w * (16 * 72);

  for (int t0 = 0; t0 < S_LEN; t0 += 64) {
    __syncthreads();
#pragma unroll
    for (int i = 0; i < 2; ++i) {
      const int c = i * 256 + tid;
      const int r = c >> 3, c8 = (c & 7) << 3;
      *(uint4*)(&Ks[r * 72 + c8]) = *(const uint4*)(Kx + (size_t)(t0 + r) * DK_ + hk + c8);
      *(uint4*)(&Vs[r * 72 + c8]) = *(const uint4*)(Vt + (size_t)(hk + r) * S_LEN + t0 + c8);
    }
    __syncthreads();

    // swapped QK^T: sT[tf] = K-rows x Q-rows; D: row = t local, col = q
    f32x4 sT[4];
#pragma unroll
    for (int tf = 0; tf < 4; ++tf) sT[tf] = z4;
#pragma unroll
    for (int ks = 0; ks < 2; ++ks) {
      bf16x8 ak[4];
#pragma unroll
      for (int tf = 0; tf < 4; ++tf)
        ak[tf] = *(const bf16x8*)(&Ks[(tf * 16 + l15) * 72 + ks * 32 + l4 * 8]);
      __builtin_amdgcn_s_setprio(1);
#pragma unroll
      for (int tf = 0; tf < 4; ++tf)
        sT[tf] = __builtin_amdgcn_mfma_f32_16x16x32_bf16(ak[tf], bq[ks], sT[tf], 0, 0, 0);
      __builtin_amdgcn_s_setprio(0);
    }

    // exp + in-lane denom partial + vectorized P staging.
    // lane holds q = q0 + l15; t = tf*16 + l4*4 + j  (4 contiguous t per frag)
    float part = 0.f;
#pragma unroll
    for (int tf = 0; tf < 4; ++tf) {
      const float e0 = __expf(sT[tf][0] * scale);
      const float e1 = __expf(sT[tf][1] * scale);
      const float e2 = __expf(sT[tf][2] * scale);
      const float e3 = __expf(sT[tf][3] * scale);
      part += (e0 + e1) + (e2 + e3);
      ushort4 pk;
      pk.x = f2b(e0); pk.y = f2b(e1); pk.z = f2b(e2); pk.w = f2b(e3);
      *(ushort4*)(&Ew[l15 * 72 + tf * 16 + l4 * 4]) = pk;
    }
    part += __shfl_xor(part, 16);
    part += __shfl_xor(part, 32);
    denom += part;

    // PV: o[nt] += P[q, t] @ V[t, hd]
#pragma unroll
    for (int ks = 0; ks < 2; ++ks) {
      const bf16x8 ae = *(const bf16x8*)(&Ew[l15 * 72 + ks * 32 + l4 * 8]);
      bf16x8 bv[4];
#pragma unroll
      for (int nt = 0; nt < 4; ++nt)
        bv[nt] = *(const bf16x8*)(&Vs[(nt * 16 + l15) * 72 + ks * 32 + l4 * 8]);
      __builtin_amdgcn_s_setprio(1);
#pragma unroll
      for (int nt = 0; nt < 4; ++nt)
        o[nt] = __builtin_amdgcn_mfma_f32_16x16x32_bf16(ae, bv[nt], o[nt], 0, 0, 0);
      __builtin_amdgcn_s_setprio(0);
    }
  }

  // normalize + store. o D-layout: row q local = l4*4+j, col d = nt*16+l15.
  // denom lives in lanes with l15 == q local -> 4 shuffles.
  float dn[4];
#pragma unroll
  for (int j = 0; j < 4; ++j)
    dn[j] = __shfl(denom, l4 * 4 + j) + 1.0f;
#pragma unroll
  for (int nt = 0; nt < 4; ++nt)
#pragma unroll
    for (int j = 0; j < 4; ++j) {
      O[(size_t)(q0 + l4 * 4 + j) * D_MODEL + h * 64 + nt * 16 + l15] =
          f2b(o[nt][j] / dn[j]);
    }
}

// ---------------------------------------------------------------------------
extern "C" void kernel_launch(void* const* d_in, const int* in_sizes, int n_in,
                              void* d_out, int out_size, void* d_ws, size_t ws_size,
                              hipStream_t stream) {
  const float* x  = (const float*)d_in[0];
  const float* pm = (const float*)d_in[1];
  const float* Wq = (const float*)d_in[2];
  const float* Wk = (const float*)d_in[3];
  const float* Wv = (const float*)d_in[4];
  const float* Wo = (const float*)d_in[5];
  float* outp = (float*)d_out;
  char* ws = (char*)d_ws;

  const size_t MB = 1024 * 1024;
  u16* xb   = (u16*)(ws + 0 * MB);    // x bf16             [2048][2048]  8MB
  u16* wqb  = (u16*)(ws + 8 * MB);    // Wq bf16 (wqkv[0])  [2048][2048]  8MB
  u16* wkb  = (u16*)(ws + 16 * MB);   // Wk bf16 (wqkv[1])  [512][2048]   2MB
  u16* wvb  = (u16*)(ws + 18 * MB);   // Wv bf16 (wqkv[2])  [512][2048]   2MB
  u16* wob  = (u16*)(ws + 20 * MB);   // Wo bf16            [2048][2048]  8MB
  u16* qro  = (u16*)(ws + 28 * MB);   // rope(xq) bf16      [2048][2048]  8MB
  u16* kro  = (u16*)(ws + 36 * MB);   // rope(xk) bf16      [2048][512]   2MB
  u16* xvb  = (u16*)(ws + 38 * MB);   // xv bf16            [2048][512]   2MB
  u16* xvt  = (u16*)(ws + 40 * MB);   // xv^T bf16          [512][2048]   2MB
  u16* attn = (u16*)(ws + 42 * MB);   // attn out bf16      [2048][2048]  8MB
  const u16* wqkv = wqb;              // contiguous [3072][2048]

  cast_all_kernel<<<14336, 256, 0, stream>>>(x, Wq, Wk, Wv, Wo, xb, wqb, wkb, wvb, wob);
  // fused QKV projection (N = 2048 Q + 512 K + 512 V), rope epilogues fused
  gemm_bt<1><<<dim3(24, 16), 256, 0, stream>>>(xb, wqkv, (void*)qro, (void*)kro,
                                               (void*)xvb, 2048, 3072, 2048, pm);
  // V transpose for t-contiguous PV reads
  transpose_bf16<<<dim3(16, 64), dim3(32, 8), 0, stream>>>(xvb, xvt, 2048, 512);
  // fused attention
  attn_kernel<<<dim3(32, 32), 256, 0, stream>>>(qro, kro, xvt, attn);
  // output projection, fp32 out
  gemm_bt<2><<<dim3(16, 16), 256, 0, stream>>>(attn, wob, (void*)outp, nullptr,
                                               nullptr, 2048, 2048, 2048, nullptr);
}

// Round 5
// 174.777 us; speedup vs baseline: 1.7220x; 1.1395x over previous
//
#include <hip/hip_runtime.h>

typedef unsigned short u16;
typedef unsigned int u32;
typedef __bf16 bf16x8 __attribute__((ext_vector_type(8)));
typedef float f32x4 __attribute__((ext_vector_type(4)));

#define S_LEN 2048
#define D_MODEL 2048
#define DK_ 512
#define PM1_OFF 4194304   // offset of pm[1] in floats (1*1*2048*2048)

__device__ __forceinline__ u16 f2b(float f) {
  u32 u = __float_as_uint(f);
  return (u16)((u + 0x7fffu + ((u >> 16) & 1u)) >> 16);
}

__device__ __forceinline__ void gload_lds16(const void* gp, void* lp) {
  __builtin_amdgcn_global_load_lds(
      (const __attribute__((address_space(1))) void*)gp,
      (__attribute__((address_space(3))) void*)lp, 16, 0, 0);
}

// ---------------- fused fp32 -> bf16 cast of x, Wq, Wk, Wv, Wo ----------------
__global__ __launch_bounds__(256) void cast_all_kernel(
    const float* __restrict__ x, const float* __restrict__ wq,
    const float* __restrict__ wk, const float* __restrict__ wv,
    const float* __restrict__ wo,
    u16* __restrict__ xb, u16* __restrict__ wqb, u16* __restrict__ wkb,
    u16* __restrict__ wvb, u16* __restrict__ wob)
{
  long i4 = (long)blockIdx.x * 256 + threadIdx.x;  // vec4 index
  const float* src; u16* dst; long off;
  if (i4 < 1048576)       { src = x;  dst = xb;  off = i4; }
  else if (i4 < 2097152)  { src = wq; dst = wqb; off = i4 - 1048576; }
  else if (i4 < 2359296)  { src = wk; dst = wkb; off = i4 - 2097152; }
  else if (i4 < 2621440)  { src = wv; dst = wvb; off = i4 - 2359296; }
  else                    { src = wo; dst = wob; off = i4 - 2621440; }
  float4 v = *(const float4*)(src + off * 4);
  ushort4 o;
  o.x = f2b(v.x); o.y = f2b(v.y); o.z = f2b(v.z); o.w = f2b(v.w);
  *(ushort4*)(dst + off * 4) = o;
}

// ---------------- GEMM: C = A @ B^T.  A[M,K], B[N,K] bf16 row-major ----------
// Tile 64(M) x 128(N), BK=64, 4 waves (2x2), each wave 32x64 -> acc[2][4].
// Staging via global_load_lds dwordx4, linear LDS.
// EPI 1: fused QKV epilogue (n<2048: rope-Q -> C0; n<2560: rope-K -> C1;
//        else plain V -> C2), bf16 stores.
// EPI 2: plain fp32 store to C0.
template<int EPI>
__global__ __launch_bounds__(256) void gemm_bt(
    const u16* __restrict__ A, const u16* __restrict__ B,
    void* __restrict__ C0, void* __restrict__ C1, void* __restrict__ C2,
    int M, int N, int K, const float* __restrict__ pm)
{
  __shared__ u16 As[64 * 64];
  __shared__ u16 Bs[128 * 64];
  const int tid = threadIdx.x;
  const int lane = tid & 63, w = tid >> 6;
  const int wr = w >> 1, wc = w & 1;
  const int l15 = lane & 15, l4 = lane >> 4;
  const int m0 = blockIdx.y * 64, n0 = blockIdx.x * 128;

  // staging: 256 threads x 16B = 4 KB/issue = 32 rows of 64 u16.
  // thread tid -> row (tid>>3), u16 col (tid&7)*8. LDS dest is wave-uniform
  // base + lane*16 (global_load_lds constraint) which matches this layout.
  const int srow = tid >> 3;           // 0..31
  const int scol = (tid & 7) << 3;     // u16 col
  char* lA = (char*)As + ((tid >> 6) << 10);   // wave-uniform base
  char* lB = (char*)Bs + ((tid >> 6) << 10);
  const u16* gA = A + (size_t)(m0 + srow) * K + scol;
  const u16* gB = B + (size_t)(n0 + srow) * K + scol;

  const f32x4 z4 = {0.f, 0.f, 0.f, 0.f};
  f32x4 acc[2][4];
#pragma unroll
  for (int i = 0; i < 2; ++i)
#pragma unroll
    for (int j = 0; j < 4; ++j) acc[i][j] = z4;

  for (int kt = 0; kt < K; kt += 64) {
    __syncthreads();
#pragma unroll
    for (int i = 0; i < 2; ++i)
      gload_lds16(gA + (size_t)(i * 32) * K + kt, lA + i * 4096);
#pragma unroll
    for (int i = 0; i < 4; ++i)
      gload_lds16(gB + (size_t)(i * 32) * K + kt, lB + i * 4096);
    __syncthreads();
#pragma unroll
    for (int ks = 0; ks < 2; ++ks) {
      bf16x8 a[2], b[4];
#pragma unroll
      for (int mt = 0; mt < 2; ++mt)
        a[mt] = *(const bf16x8*)(&As[(wr * 32 + mt * 16 + l15) * 64 + ks * 32 + l4 * 8]);
#pragma unroll
      for (int nt = 0; nt < 4; ++nt)
        b[nt] = *(const bf16x8*)(&Bs[(wc * 64 + nt * 16 + l15) * 64 + ks * 32 + l4 * 8]);
#pragma unroll
      for (int mt = 0; mt < 2; ++mt)
#pragma unroll
        for (int nt = 0; nt < 4; ++nt)
          acc[mt][nt] = __builtin_amdgcn_mfma_f32_16x16x32_bf16(a[mt], b[nt], acc[mt][nt], 0, 0, 0);
    }
  }

#pragma unroll
  for (int mt = 0; mt < 2; ++mt)
#pragma unroll
    for (int nt = 0; nt < 4; ++nt)
#pragma unroll
      for (int j = 0; j < 4; ++j) {
        const int m = m0 + wr * 32 + mt * 16 + l4 * 4 + j;
        const int n = n0 + wc * 64 + nt * 16 + l15;
        const float v = acc[mt][nt][j];
        if (EPI == 2) {
          ((float*)C0)[(size_t)m * N + n] = v;
        } else {
          if (n < 2048) {          // Q range, rope d=2048
            const int jj = (n < 1024) ? (n + 1024) : (n - 1024);
            const float sv = (n < 1024) ? v : -v;
            const float p = pm[(size_t)m * D_MODEL + jj] +
                            pm[PM1_OFF + (size_t)m * D_MODEL + jj];
            ((u16*)C0)[(size_t)m * D_MODEL + jj] = f2b(sv * p);
          } else if (n < 2560) {   // K range, rope d=512
            const int nn = n - 2048;
            const int jj = (nn < 256) ? (nn + 256) : (nn - 256);
            const float sv = (nn < 256) ? v : -v;
            const float p = pm[(size_t)m * D_MODEL + jj] +
                            pm[PM1_OFF + (size_t)m * D_MODEL + jj];
            ((u16*)C1)[(size_t)m * DK_ + jj] = f2b(sv * p);
          } else {                 // V range, plain
            ((u16*)C2)[(size_t)m * DK_ + (n - 2560)] = f2b(v);
          }
        }
      }
}

// ---------------- bf16 transpose: in[R][C] -> out[C][R] ----------------------
__global__ __launch_bounds__(256) void transpose_bf16(
    const u16* __restrict__ in, u16* __restrict__ out, int R, int C)
{
  __shared__ u16 t[32][33];
  const int c0 = blockIdx.x * 32, r0 = blockIdx.y * 32;
  const int x = threadIdx.x, y = threadIdx.y;  // blockDim = (32, 8)
#pragma unroll
  for (int j = 0; j < 32; j += 8)
    t[y + j][x] = in[(size_t)(r0 + y + j) * C + c0 + x];
  __syncthreads();
#pragma unroll
  for (int j = 0; j < 32; j += 8)
    out[(size_t)(c0 + y + j) * R + r0 + x] = t[x][y + j];
}

// ---------------- fused attention (swapped QK^T) -----------------------------
// Q: qro [S][2048] bf16. Kx: kro [S][512] bf16. Vt: xv^T [512][S] bf16.
// O: attn out [S][2048] bf16. Block: 256 thr = 4 waves; each wave owns 16 q
// rows; KV tiles of 64. Grid (32, 32) = 1024 blocks -> 16 waves/CU.
// Swapped QK^T: sT = mfma(K, Q) => lane's 4 P-values per frag are
// t-contiguous -> vectorized b64 stores into Es, in-lane denom reduce.
__global__ __launch_bounds__(256) void attn_kernel(
    const u16* __restrict__ Q, const u16* __restrict__ Kx,
    const u16* __restrict__ Vt, u16* __restrict__ O)
{
  __shared__ u16 Ks[64 * 72];        // K tile [t][hd], stride 72 (pad)
  __shared__ u16 Vs[64 * 72];        // V^T tile [hd][t], stride 72
  __shared__ u16 Es[4 * 16 * 72];    // per-wave P tile [q][t], stride 72

  const int tid = threadIdx.x;
  const int lane = tid & 63, w = tid >> 6;
  const int l15 = lane & 15, l4 = lane >> 4;
  const int h = blockIdx.y;
  const int q0 = blockIdx.x * 64 + w * 16;
  const int hk = (h & 7) * 64;       // kv column base (GQA: kv head = h%8)
  const float scale = 0.04419417187f;  // 1/(sqrt(512)+1e-6)

  // Q as B-operand: row q = q0+l15, k-elems hd = ks*32 + l4*8 ..+7
  bf16x8 bq[2];
#pragma unroll
  for (int ks = 0; ks < 2; ++ks)
    bq[ks] = *(const bf16x8*)(Q + (size_t)(q0 + l15) * D_MODEL + h * 64 + ks * 32 + l4 * 8);

  const f32x4 z4 = {0.f, 0.f, 0.f, 0.f};
  f32x4 o[4];
#pragma unroll
  for (int nt = 0; nt < 4; ++nt) o[nt] = z4;
  float denom = 0.f;

  u16* Ew = Es + w * (16 * 72);

  for (int t0 = 0; t0 < S_LEN; t0 += 64) {
    __syncthreads();
#pragma unroll
    for (int i = 0; i < 2; ++i) {
      const int c = i * 256 + tid;
      const int r = c >> 3, c8 = (c & 7) << 3;
      *(uint4*)(&Ks[r * 72 + c8]) = *(const uint4*)(Kx + (size_t)(t0 + r) * DK_ + hk + c8);
      *(uint4*)(&Vs[r * 72 + c8]) = *(const uint4*)(Vt + (size_t)(hk + r) * S_LEN + t0 + c8);
    }
    __syncthreads();

    // swapped QK^T: sT[tf] = K-rows x Q-rows; D: row = t local, col = q
    f32x4 sT[4];
#pragma unroll
    for (int tf = 0; tf < 4; ++tf) sT[tf] = z4;
#pragma unroll
    for (int ks = 0; ks < 2; ++ks) {
      bf16x8 ak[4];
#pragma unroll
      for (int tf = 0; tf < 4; ++tf)
        ak[tf] = *(const bf16x8*)(&Ks[(tf * 16 + l15) * 72 + ks * 32 + l4 * 8]);
      __builtin_amdgcn_s_setprio(1);
#pragma unroll
      for (int tf = 0; tf < 4; ++tf)
        sT[tf] = __builtin_amdgcn_mfma_f32_16x16x32_bf16(ak[tf], bq[ks], sT[tf], 0, 0, 0);
      __builtin_amdgcn_s_setprio(0);
    }

    // exp + in-lane denom partial + vectorized P staging.
    // lane holds q = q0 + l15; t = tf*16 + l4*4 + j  (4 contiguous t per frag)
    float part = 0.f;
#pragma unroll
    for (int tf = 0; tf < 4; ++tf) {
      const float e0 = __expf(sT[tf][0] * scale);
      const float e1 = __expf(sT[tf][1] * scale);
      const float e2 = __expf(sT[tf][2] * scale);
      const float e3 = __expf(sT[tf][3] * scale);
      part += (e0 + e1) + (e2 + e3);
      ushort4 pk;
      pk.x = f2b(e0); pk.y = f2b(e1); pk.z = f2b(e2); pk.w = f2b(e3);
      *(ushort4*)(&Ew[l15 * 72 + tf * 16 + l4 * 4]) = pk;
    }
    part += __shfl_xor(part, 16);
    part += __shfl_xor(part, 32);
    denom += part;

    // PV: o[nt] += P[q, t] @ V[t, hd]
#pragma unroll
    for (int ks = 0; ks < 2; ++ks) {
      const bf16x8 ae = *(const bf16x8*)(&Ew[l15 * 72 + ks * 32 + l4 * 8]);
      bf16x8 bv[4];
#pragma unroll
      for (int nt = 0; nt < 4; ++nt)
        bv[nt] = *(const bf16x8*)(&Vs[(nt * 16 + l15) * 72 + ks * 32 + l4 * 8]);
      __builtin_amdgcn_s_setprio(1);
#pragma unroll
      for (int nt = 0; nt < 4; ++nt)
        o[nt] = __builtin_amdgcn_mfma_f32_16x16x32_bf16(ae, bv[nt], o[nt], 0, 0, 0);
      __builtin_amdgcn_s_setprio(0);
    }
  }

  // normalize + store. o D-layout: row q local = l4*4+j, col d = nt*16+l15.
  // denom lives in lanes with l15 == q local -> 4 shuffles.
  float dn[4];
#pragma unroll
  for (int j = 0; j < 4; ++j)
    dn[j] = __shfl(denom, l4 * 4 + j) + 1.0f;
#pragma unroll
  for (int nt = 0; nt < 4; ++nt)
#pragma unroll
    for (int j = 0; j < 4; ++j) {
      O[(size_t)(q0 + l4 * 4 + j) * D_MODEL + h * 64 + nt * 16 + l15] =
          f2b(o[nt][j] / dn[j]);
    }
}

// ---------------------------------------------------------------------------
extern "C" void kernel_launch(void* const* d_in, const int* in_sizes, int n_in,
                              void* d_out, int out_size, void* d_ws, size_t ws_size,
                              hipStream_t stream) {
  const float* x  = (const float*)d_in[0];
  const float* pm = (const float*)d_in[1];
  const float* Wq = (const float*)d_in[2];
  const float* Wk = (const float*)d_in[3];
  const float* Wv = (const float*)d_in[4];
  const float* Wo = (const float*)d_in[5];
  float* outp = (float*)d_out;
  char* ws = (char*)d_ws;

  const size_t MB = 1024 * 1024;
  u16* xb   = (u16*)(ws + 0 * MB);    // x bf16             [2048][2048]  8MB
  u16* wqb  = (u16*)(ws + 8 * MB);    // Wq bf16 (wqkv[0])  [2048][2048]  8MB
  u16* wkb  = (u16*)(ws + 16 * MB);   // Wk bf16 (wqkv[1])  [512][2048]   2MB
  u16* wvb  = (u16*)(ws + 18 * MB);   // Wv bf16 (wqkv[2])  [512][2048]   2MB
  u16* wob  = (u16*)(ws + 20 * MB);   // Wo bf16            [2048][2048]  8MB
  u16* qro  = (u16*)(ws + 28 * MB);   // rope(xq) bf16      [2048][2048]  8MB
  u16* kro  = (u16*)(ws + 36 * MB);   // rope(xk) bf16      [2048][512]   2MB
  u16* xvb  = (u16*)(ws + 38 * MB);   // xv bf16            [2048][512]   2MB
  u16* xvt  = (u16*)(ws + 40 * MB);   // xv^T bf16          [512][2048]   2MB
  u16* attn = (u16*)(ws + 42 * MB);   // attn out bf16      [2048][2048]  8MB
  const u16* wqkv = wqb;              // contiguous [3072][2048]

  cast_all_kernel<<<14336, 256, 0, stream>>>(x, Wq, Wk, Wv, Wo, xb, wqb, wkb, wvb, wob);
  // fused QKV projection (N = 2048 Q + 512 K + 512 V), rope epilogues fused
  gemm_bt<1><<<dim3(24, 32), 256, 0, stream>>>(xb, wqkv, (void*)qro, (void*)kro,
                                               (void*)xvb, 2048, 3072, 2048, pm);
  // V transpose for t-contiguous PV reads
  transpose_bf16<<<dim3(16, 64), dim3(32, 8), 0, stream>>>(xvb, xvt, 2048, 512);
  // fused attention
  attn_kernel<<<dim3(32, 32), 256, 0, stream>>>(qro, kro, xvt, attn);
  // output projection, fp32 out
  gemm_bt<2><<<dim3(16, 32), 256, 0, stream>>>(attn, wob, (void*)outp, nullptr,
                                               nullptr, 2048, 2048, 2048, nullptr);
}